// Round 10
// baseline (715.053 us; speedup 1.0000x reference)
//
#include <hip/hip_runtime.h>
#include <stdint.h>

#define SEQ   2048
#define BATCH 4
#define NH    16
#define HD    64
#define DIMN  1024
#define MROWS (BATCH*SEQ)   // 8192

typedef __attribute__((ext_vector_type(8)))  short          bf16x8;
typedef __attribute__((ext_vector_type(8)))  unsigned short ushort8;
typedef __attribute__((ext_vector_type(4)))  float          f32x4;
typedef __attribute__((ext_vector_type(16))) float          f32x16;

static __device__ __forceinline__ unsigned short f2bf(float f) {
    unsigned int u = __builtin_bit_cast(unsigned int, f);
    u += 0x7fffu + ((u >> 16) & 1u);          // RNE
    return (unsigned short)(u >> 16);
}
// RNE-ish (round-half-up) pack: 3 ops
static __device__ __forceinline__ unsigned int pack2bf(float lo, float hi) {
    unsigned int a = __builtin_bit_cast(unsigned int, lo) + 0x8000u;
    unsigned int b = __builtin_bit_cast(unsigned int, hi) + 0x8000u;
    return __builtin_amdgcn_perm(b, a, 0x07060302u);
}
// truncating pack: 1 op (P in [0,1], rel err <= 2^-8, fine for softmax weights)
static __device__ __forceinline__ unsigned int pack2bf_trunc(float lo, float hi) {
    return __builtin_amdgcn_perm(__builtin_bit_cast(unsigned int, hi),
                                 __builtin_bit_cast(unsigned int, lo), 0x07060302u);
}

// ---------------------------------------------------------------- fused prologue
__global__ __launch_bounds__(256) void prologue_kernel(
        const float* __restrict__ x,
        const float* __restrict__ qw, const float* __restrict__ kw,
        const float* __restrict__ vw, const float* __restrict__ ow,
        unsigned short* __restrict__ xb,
        unsigned short* __restrict__ wq, unsigned short* __restrict__ wk,
        unsigned short* __restrict__ wv, unsigned short* __restrict__ wo,
        float* __restrict__ cosT, float* __restrict__ sinT,
        const unsigned char* __restrict__ mask, unsigned long long* __restrict__ m64) {
    const int bx = blockIdx.x, tid = threadIdx.x;
    if (bx < 4096 + 2048) {
        const float* s; unsigned short* d; int i;
        if (bx < 4096) { s = x; d = xb; i = bx * 2048 + tid * 8; }
        else {
            int wb = bx - 4096;
            int wsel = wb >> 9;
            s = wsel == 0 ? qw : (wsel == 1 ? kw : (wsel == 2 ? vw : ow));
            d = wsel == 0 ? wq : (wsel == 1 ? wk : (wsel == 2 ? wv : wo));
            i = (wb & 511) * 2048 + tid * 8;
        }
        float4 a = *(const float4*)(s + i);
        float4 b = *(const float4*)(s + i + 4);
        ushort8 o;
        o[0]=f2bf(a.x); o[1]=f2bf(a.y); o[2]=f2bf(a.z); o[3]=f2bf(a.w);
        o[4]=f2bf(b.x); o[5]=f2bf(b.y); o[6]=f2bf(b.z); o[7]=f2bf(b.w);
        *(ushort8*)(d + i) = o;
    } else if (bx < 6400) {
        int idx = (bx - 6144) * 256 + tid;        // SEQ*32
        int s = idx >> 5, j = idx & 31;
        float t = (float)(2 * j) / 64.0f;
        float freq = 1.0f / powf(10000.0f, t);
        float ang  = (float)s * freq;
        cosT[idx] = cosf(ang);
        sinT[idx] = sinf(ang);
    } else {
        if (tid < 128) {
            int b = tid >> 5, kt = tid & 31;
            const unsigned char* p = mask + b * SEQ + kt * 64;
            unsigned long long v = 0;
            for (int j = 0; j < 64; j++) v |= (unsigned long long)(p[j] != 0) << j;
            m64[tid] = v;
        }
    }
}

// ---------------------------------------------------------------- fused Q,K,V^T GEMM
// (R6 version) LDS double-buffer + early stage; ONE barrier per 32-step;
// chunk XOR swizzle.
__global__ __launch_bounds__(256) void gemm_qkvt(const unsigned short* __restrict__ X,
        const unsigned short* __restrict__ Wq, const unsigned short* __restrict__ Wk,
        const unsigned short* __restrict__ Wv,
        const float* __restrict__ bq, const float* __restrict__ bk, const float* __restrict__ bv,
        unsigned short* __restrict__ Qo, unsigned short* __restrict__ Ko, unsigned short* __restrict__ Vto,
        const float* __restrict__ cosT, const float* __restrict__ sinT) {
    __shared__ __align__(16) unsigned short As0[128 * 32];
    __shared__ __align__(16) unsigned short Bs0[128 * 32];
    __shared__ __align__(16) unsigned short As1[128 * 32];
    __shared__ __align__(16) unsigned short Bs1[128 * 32];
    const int which = blockIdx.x >> 3;
    const int tid  = threadIdx.x;
    const int wid  = tid >> 6, lane = tid & 63;
    const int quad = lane >> 4, l15 = lane & 15;
    const int wm   = wid >> 1,  wn  = wid & 1;

    const unsigned short *Ag, *Bg;
    int m0, n0;
    if (which < 2) {
        m0 = blockIdx.y * 128;                 // token rows
        n0 = (blockIdx.x & 7) * 128;           // embed cols
        Ag = X;  Bg = which == 0 ? Wq : Wk;
    } else {
        m0 = (blockIdx.x & 7) * 128;           // e rows
        n0 = blockIdx.y * 128;                 // token rows
        Ag = Wv; Bg = X;
    }

    f32x4 acc[4][4];
#pragma unroll
    for (int i = 0; i < 4; i++)
#pragma unroll
        for (int j = 0; j < 4; j++) acc[i][j] = (f32x4)0.0f;

    const int rb = wid * 32 + (lane >> 2);
    const int cb = (((lane & 3) ^ ((lane >> 3) & 3)) * 8);
    const int rq = (quad ^ ((l15 >> 1) & 3)) * 8;

#define GSTAGE(BA, BB, KK) do {                                                             \
    _Pragma("unroll")                                                                       \
    for (int i_ = 0; i_ < 2; i_++) {                                                        \
        const unsigned short* ga_ = Ag + (size_t)(m0 + rb + i_ * 16) * DIMN + (KK) + cb;    \
        __builtin_amdgcn_global_load_lds((const __attribute__((address_space(1))) void*)ga_,\
            (__attribute__((address_space(3))) void*)&BA[(wid * 32 + i_ * 16) * 32], 16, 0, 0);\
        const unsigned short* gb_ = Bg + (size_t)(n0 + rb + i_ * 16) * DIMN + (KK) + cb;    \
        __builtin_amdgcn_global_load_lds((const __attribute__((address_space(1))) void*)gb_,\
            (__attribute__((address_space(3))) void*)&BB[(wid * 32 + i_ * 16) * 32], 16, 0, 0);\
    } } while (0)

#define GCOMP(BA, BB) do {                                                                  \
    bf16x8 af_[4], bf_[4];                                                                  \
    _Pragma("unroll")                                                                       \
    for (int f_ = 0; f_ < 4; f_++) af_[f_] = *(const bf16x8*)&BA[(wm * 64 + f_ * 16 + l15) * 32 + rq]; \
    _Pragma("unroll")                                                                       \
    for (int f_ = 0; f_ < 4; f_++) bf_[f_] = *(const bf16x8*)&BB[(wn * 64 + f_ * 16 + l15) * 32 + rq]; \
    _Pragma("unroll")                                                                       \
    for (int fm_ = 0; fm_ < 4; fm_++)                                                       \
        _Pragma("unroll")                                                                   \
        for (int fn_ = 0; fn_ < 4; fn_++)                                                   \
            acc[fm_][fn_] = __builtin_amdgcn_mfma_f32_16x16x32_bf16(af_[fm_], bf_[fn_], acc[fm_][fn_], 0, 0, 0); \
    } while (0)

    GSTAGE(As0, Bs0, 0);
    for (int k0 = 0; k0 < DIMN; k0 += 64) {
        __syncthreads();                           // As0/Bs0 ready
        GSTAGE(As1, Bs1, k0 + 32);                 // issue next into other buffer
        GCOMP(As0, Bs0);
        __syncthreads();                           // As1/Bs1 ready
        if (k0 + 64 < DIMN) GSTAGE(As0, Bs0, k0 + 64);
        GCOMP(As1, Bs1);
    }

    if (which < 2) {                            // Q or K: +bias, scale, RoPE, [B,H,S,D]
        const float* bias   = which == 0 ? bq : bk;
        unsigned short* Out = which == 0 ? Qo : Ko;
        const float scale = which == 0 ? 0.18033688011112042f : 1.0f;  // 0.125*log2e
        float bv4[4];
#pragma unroll
        for (int fn = 0; fn < 4; fn++) bv4[fn] = bias[n0 + wn * 64 + fn * 16 + l15];
        const int h = (n0 >> 6) + wn;
#pragma unroll
        for (int fm = 0; fm < 4; fm++)
#pragma unroll
            for (int r = 0; r < 4; r++) {
                int mrow = m0 + wm * 64 + fm * 16 + quad * 4 + r;
                int b = mrow >> 11, s = mrow & (SEQ - 1);
                unsigned short* orow = Out + ((size_t)(b * NH + h) * SEQ + s) * HD;
                float v0 = (acc[fm][0][r] + bv4[0]) * scale;
                float v1 = (acc[fm][1][r] + bv4[1]) * scale;
                float v2 = (acc[fm][2][r] + bv4[2]) * scale;
                float v3 = (acc[fm][3][r] + bv4[3]) * scale;
                int d0 = l15, d1 = 16 + l15;
                float c0 = cosT[s * 32 + d0], s0 = sinT[s * 32 + d0];
                float c1 = cosT[s * 32 + d1], s1 = sinT[s * 32 + d1];
                orow[d0]      = f2bf(v0 * c0 - v2 * s0);
                orow[d0 + 32] = f2bf(v0 * s0 + v2 * c0);
                orow[d1]      = f2bf(v1 * c1 - v3 * s1);
                orow[d1 + 32] = f2bf(v1 * s1 + v3 * c1);
            }
    } else {                                    // V^T: [B,H,D,S]
        float4 bb[4];
#pragma unroll
        for (int fm = 0; fm < 4; fm++)
            bb[fm] = *(const float4*)&bv[m0 + wm * 64 + fm * 16 + quad * 4];
        const int b     = n0 >> 11;
        const int sbase = (n0 & (SEQ - 1)) + wn * 64 + l15;
#pragma unroll
        for (int fm = 0; fm < 4; fm++)
#pragma unroll
            for (int r = 0; r < 4; r++) {
                int e = m0 + wm * 64 + fm * 16 + quad * 4 + r;
                float bval = r == 0 ? bb[fm].x : (r == 1 ? bb[fm].y : (r == 2 ? bb[fm].z : bb[fm].w));
                unsigned short* row = Vto + ((size_t)(b * NH + (e >> 6)) * HD + (e & 63)) * SEQ + sbase;
#pragma unroll
                for (int fn = 0; fn < 4; fn++)
                    row[fn * 16] = f2bf(acc[fm][fn][r] + bval);
            }
    }
#undef GSTAGE
#undef GCOMP
}

// ---------------------------------------------------------------- output-proj GEMM (fp32 out)
__global__ __launch_bounds__(256) void gemm_bt(const unsigned short* __restrict__ A,
                                               const unsigned short* __restrict__ W,
                                               const float* __restrict__ bias,
                                               float* __restrict__ out) {
    __shared__ __align__(16) unsigned short As0[128 * 32];
    __shared__ __align__(16) unsigned short Bs0[128 * 32];
    __shared__ __align__(16) unsigned short As1[128 * 32];
    __shared__ __align__(16) unsigned short Bs1[128 * 32];
    const int tid  = threadIdx.x;
    const int wid  = tid >> 6, lane = tid & 63;
    const int quad = lane >> 4, l15 = lane & 15;
    const int wm   = wid >> 1,  wn  = wid & 1;
    const int m0   = blockIdx.y * 128, n0 = blockIdx.x * 128;

    f32x4 acc[4][4];
#pragma unroll
    for (int i = 0; i < 4; i++)
#pragma unroll
        for (int j = 0; j < 4; j++) acc[i][j] = (f32x4)0.0f;

    const int rb = wid * 32 + (lane >> 2);
    const int cb = (((lane & 3) ^ ((lane >> 3) & 3)) * 8);
    const int rq = (quad ^ ((l15 >> 1) & 3)) * 8;

#define GSTAGE(BA, BB, KK) do {                                                             \
    _Pragma("unroll")                                                                       \
    for (int i_ = 0; i_ < 2; i_++) {                                                        \
        const unsigned short* ga_ = A + (size_t)(m0 + rb + i_ * 16) * DIMN + (KK) + cb;     \
        __builtin_amdgcn_global_load_lds((const __attribute__((address_space(1))) void*)ga_,\
            (__attribute__((address_space(3))) void*)&BA[(wid * 32 + i_ * 16) * 32], 16, 0, 0);\
        const unsigned short* gb_ = W + (size_t)(n0 + rb + i_ * 16) * DIMN + (KK) + cb;     \
        __builtin_amdgcn_global_load_lds((const __attribute__((address_space(1))) void*)gb_,\
            (__attribute__((address_space(3))) void*)&BB[(wid * 32 + i_ * 16) * 32], 16, 0, 0);\
    } } while (0)

#define GCOMP(BA, BB) do {                                                                  \
    bf16x8 af_[4], bf_[4];                                                                  \
    _Pragma("unroll")                                                                       \
    for (int f_ = 0; f_ < 4; f_++) af_[f_] = *(const bf16x8*)&BA[(wm * 64 + f_ * 16 + l15) * 32 + rq]; \
    _Pragma("unroll")                                                                       \
    for (int f_ = 0; f_ < 4; f_++) bf_[f_] = *(const bf16x8*)&BB[(wn * 64 + f_ * 16 + l15) * 32 + rq]; \
    _Pragma("unroll")                                                                       \
    for (int fm_ = 0; fm_ < 4; fm_++)                                                       \
        _Pragma("unroll")                                                                   \
        for (int fn_ = 0; fn_ < 4; fn_++)                                                   \
            acc[fm_][fn_] = __builtin_amdgcn_mfma_f32_16x16x32_bf16(af_[fm_], bf_[fn_], acc[fm_][fn_], 0, 0, 0); \
    } while (0)

    GSTAGE(As0, Bs0, 0);
    for (int k0 = 0; k0 < DIMN; k0 += 64) {
        __syncthreads();
        GSTAGE(As1, Bs1, k0 + 32);
        GCOMP(As0, Bs0);
        __syncthreads();
        if (k0 + 64 < DIMN) GSTAGE(As0, Bs0, k0 + 64);
        GCOMP(As1, Bs1);
    }

    float bv4[4];
#pragma unroll
    for (int fn = 0; fn < 4; fn++) bv4[fn] = bias[n0 + wn * 64 + fn * 16 + l15];
#pragma unroll
    for (int fm = 0; fm < 4; fm++)
#pragma unroll
        for (int r = 0; r < 4; r++) {
            int mrow = m0 + wm * 64 + fm * 16 + quad * 4 + r;
            float* orow = out + (size_t)mrow * DIMN + n0 + wn * 64;
#pragma unroll
            for (int fn = 0; fn < 4; fn++) orow[fn * 16 + l15] = acc[fm][fn][r] + bv4[fn];
        }
#undef GSTAGE
#undef GCOMP
}

// ---------------------------------------------------------------- flash attention v15 (split-K stage 1)
// R9 fix: R8's NaN was a WORKSPACE OVERLAP (Qb/Kb/Vtb spacing halved to 4M
// elements while Q needs 8M; Opart at 49 MiB overlapped Vtb). Kernels were
// fine. Layout restored: Qb/Kb/Vtb at 25/41/57 MiB (16 MiB each), Opart at
// 73 MiB, Lpart at 137 MiB; guard ws_size >= 138 MiB.
// Theory (unchanged): v13 is dependency-stall bound (demand ~40us/CU vs 88
// measured); grid 1024 = 4 blk/CU = 50% occupancy. Split each q-tile's keys
// across 2 blocks -> grid 2048 -> 8 blk/CU = 32 waves = 100% occupancy.
// Exp2-domain no-max softmax => partials combine by simple ADD.
__global__ __launch_bounds__(256, 8) void attn_part(const unsigned short* __restrict__ Q,
                                                    const unsigned short* __restrict__ K,
                                                    const unsigned short* __restrict__ Vt,
                                                    const unsigned long long* __restrict__ M64,
                                                    float* __restrict__ Opart,
                                                    float* __restrict__ Lpart) {
    __shared__ __align__(16) unsigned short Kls[64 * 64];   // 8 KiB [token][k]
    __shared__ __align__(16) unsigned short Vls[64 * 64];   // 8 KiB [d][token]

    const int tid  = threadIdx.x;
    const int wid  = tid >> 6, lane = tid & 63;
    const int hi   = lane >> 5, l31 = lane & 31, l7 = lane & 7;
    // bid = xcd + 8*(sh + 2*qt) + 256*hi8; bh = xcd*8 + hi8 -> all 32 blocks
    // of a (b,h) stay on one XCD (K/V L2-resident).
    const int bid = blockIdx.x;
    const int bh  = (bid & 7) * 8 + (bid >> 8);
    const int mid = (bid >> 3) & 31;
    const int qt  = mid >> 1, sh = mid & 1;
    const int b = bh >> 4;
    const int q0 = qt * 128;

    bf16x8 qB[4];
    {
        const unsigned short* qrow = Q + ((size_t)bh * SEQ + q0 + wid * 32 + l31) * HD + hi * 8;
#pragma unroll
        for (int ks = 0; ks < 4; ks++)
            qB[ks] = __builtin_bit_cast(bf16x8, *(const uint4*)(qrow + ks * 16));
    }

    f32x16 Oa[2];                 // O^T tiles: d = dt*32 + (r&3)+8*(r>>2)+4*hi, q = l31
    Oa[0] = (f32x16)0.0f;
    Oa[1] = (f32x16)0.0f;
    float ls = 0.0f;

    const unsigned long long* Mrow = M64 + b * (SEQ / 64);

    const int srow = lane >> 3;
    const int sgr  = ((lane & 7) ^ ((lane >> 3) & 7)) * 8;
    const unsigned short* Kg = K  + (size_t)bh * SEQ * HD;
    const unsigned short* Vg = Vt + (size_t)bh * HD * SEQ;
    const unsigned short* Kb0 = Kg + (size_t)(wid * 16 + srow) * HD + sgr;
    const unsigned short* Vb0 = Vg + (size_t)(wid * 16 + srow) * SEQ + sgr;

    for (int kt = sh * 16; kt < sh * 16 + 16; kt++) {
        const int k0 = kt * 64;
#pragma unroll
        for (int j = 0; j < 2; j++) {
            __builtin_amdgcn_global_load_lds(
                (const __attribute__((address_space(1))) void*)(Kb0 + (size_t)(k0 + j * 8) * HD),
                (__attribute__((address_space(3))) void*)&Kls[(wid * 16 + j * 8) * 64], 16, 0, 0);
            __builtin_amdgcn_global_load_lds(
                (const __attribute__((address_space(1))) void*)(Vb0 + (size_t)(j * 8) * SEQ + k0),
                (__attribute__((address_space(3))) void*)&Vls[(wid * 16 + j * 8) * 64], 16, 0, 0);
        }
        unsigned long long mb = Mrow[kt];
        __syncthreads();

#pragma unroll
        for (int h2 = 0; h2 < 2; h2++) {
            bf16x8 kA[4];
#pragma unroll
            for (int ks = 0; ks < 4; ks++)
                kA[ks] = *(const bf16x8*)&Kls[(h2 * 32 + l31) * 64 + (((ks << 1) + hi) ^ l7) * 8];

            f32x16 st = (f32x16)0.0f;
            __builtin_amdgcn_s_setprio(1);
#pragma unroll
            for (int ks = 0; ks < 4; ks++)
                st = __builtin_amdgcn_mfma_f32_32x32x16_bf16(kA[ks], qB[ks], st, 0, 0, 0);
            __builtin_amdgcn_s_setprio(0);

            unsigned int mh = (unsigned int)(mb >> (h2 * 32));
            if (mh) {
#pragma unroll
                for (int r = 0; r < 16; r++) {
                    int kk = (r & 3) + ((r >> 2) << 3) + (hi << 2);
                    if ((mh >> kk) & 1u) st[r] = -1e9f;
                }
            }

            float p[16];
#pragma unroll
            for (int r = 0; r < 16; r++) p[r] = __builtin_amdgcn_exp2f(st[r]);
            float s01 = (p[0] + p[1]) + (p[2] + p[3]);
            float s23 = (p[4] + p[5]) + (p[6] + p[7]);
            float s45 = (p[8] + p[9]) + (p[10] + p[11]);
            float s67 = (p[12] + p[13]) + (p[14] + p[15]);
            ls += (s01 + s23) + (s45 + s67);

            unsigned int w000 = pack2bf_trunc(p[0],  p[1]);
            unsigned int w001 = pack2bf_trunc(p[2],  p[3]);
            unsigned int w010 = pack2bf_trunc(p[4],  p[5]);
            unsigned int w011 = pack2bf_trunc(p[6],  p[7]);
            unsigned int w100 = pack2bf_trunc(p[8],  p[9]);
            unsigned int w101 = pack2bf_trunc(p[10], p[11]);
            unsigned int w110 = pack2bf_trunc(p[12], p[13]);
            unsigned int w111 = pack2bf_trunc(p[14], p[15]);

            bf16x8 pB[2];
#pragma unroll
            for (int ks = 0; ks < 2; ks++) {
                unsigned int own0 = ks == 0 ? (hi ? w010 : w000) : (hi ? w110 : w100);
                unsigned int own1 = ks == 0 ? (hi ? w011 : w001) : (hi ? w111 : w101);
                unsigned int oth0 = ks == 0 ? (hi ? w000 : w010) : (hi ? w100 : w110);
                unsigned int oth1 = ks == 0 ? (hi ? w001 : w011) : (hi ? w101 : w111);
                unsigned int r0 = (unsigned int)__shfl_xor((int)oth0, 32);
                unsigned int r1 = (unsigned int)__shfl_xor((int)oth1, 32);
                uint4 pw;
                pw.x = hi ? r0 : own0;
                pw.y = hi ? r1 : own1;
                pw.z = hi ? own0 : r0;
                pw.w = hi ? own1 : r1;
                pB[ks] = __builtin_bit_cast(bf16x8, pw);
            }

            __builtin_amdgcn_s_setprio(1);
#pragma unroll
            for (int dt = 0; dt < 2; dt++)
#pragma unroll
                for (int kv = 0; kv < 2; kv++) {
                    bf16x8 vA = *(const bf16x8*)&Vls[(dt * 32 + l31) * 64 +
                                    (((h2 << 2) + (kv << 1) + hi) ^ l7) * 8];
                    Oa[dt] = __builtin_amdgcn_mfma_f32_32x32x16_bf16(vA, pB[kv], Oa[dt], 0, 0, 0);
                }
            __builtin_amdgcn_s_setprio(0);
        }
        __syncthreads();
    }

    // partial-l: reduce the two hi-halves (full 1024-key sum for q=l31)
    float lsum = ls + __shfl_xor(ls, 32);
    const int ql = wid * 32 + l31;                 // block-local q row 0..127
    const size_t part = (size_t)((bh * 16 + qt) * 2 + sh);
    if (hi == 0) Lpart[part * 128 + ql] = lsum;

    // partial-O: [128 q][64 d] f32 per (bh,qt,sh)
    float* Op = Opart + part * (128 * 64) + (size_t)ql * 64;
#pragma unroll
    for (int dt = 0; dt < 2; dt++)
#pragma unroll
        for (int rg = 0; rg < 4; rg++) {
            float4 v;
            v.x = Oa[dt][rg * 4 + 0];
            v.y = Oa[dt][rg * 4 + 1];
            v.z = Oa[dt][rg * 4 + 2];
            v.w = Oa[dt][rg * 4 + 3];
            *(float4*)(Op + dt * 32 + rg * 8 + hi * 4) = v;
        }
}

// ---------------------------------------------------------------- attn stage 2: combine + normalize
__global__ __launch_bounds__(256) void attn_norm(const float* __restrict__ Opart,
                                                 const float* __restrict__ Lpart,
                                                 unsigned short* __restrict__ Ob) {
    const int bq = blockIdx.x;            // bh*16 + qt
    const int bh = bq >> 4, qt = bq & 15;
    const int b = bh >> 4, h = bh & 15;
    const int tid = threadIdx.x;
    const int q = tid >> 1, dh = (tid & 1) * 32;

    const float l0 = Lpart[(size_t)(bq * 2 + 0) * 128 + q];
    const float l1 = Lpart[(size_t)(bq * 2 + 1) * 128 + q];
    const float linv = 1.0f / (l0 + l1);

    const float* O0 = Opart + (size_t)(bq * 2 + 0) * (128 * 64) + (size_t)q * 64 + dh;
    const float* O1 = O0 + 128 * 64;

    const int s = qt * 128 + q;
    unsigned short* orow = Ob + ((size_t)b * SEQ + s) * DIMN + h * HD + dh;
#pragma unroll
    for (int g = 0; g < 4; g++) {
        float4 a0 = *(const float4*)(O0 + g * 8);
        float4 a1 = *(const float4*)(O0 + g * 8 + 4);
        float4 c0 = *(const float4*)(O1 + g * 8);
        float4 c1 = *(const float4*)(O1 + g * 8 + 4);
        uint4 st;
        st.x = pack2bf((a0.x + c0.x) * linv, (a0.y + c0.y) * linv);
        st.y = pack2bf((a0.z + c0.z) * linv, (a0.w + c0.w) * linv);
        st.z = pack2bf((a1.x + c1.x) * linv, (a1.y + c1.y) * linv);
        st.w = pack2bf((a1.z + c1.z) * linv, (a1.w + c1.w) * linv);
        *(uint4*)(orow + g * 8) = st;
    }
}

// ---------------------------------------------------------------- flash attention v13 (fallback)
// Used when workspace is too small for the split-K partials.
__global__ __launch_bounds__(256, 4) void attn_kernel(const unsigned short* __restrict__ Q,
                                                      const unsigned short* __restrict__ K,
                                                      const unsigned short* __restrict__ Vt,
                                                      const unsigned long long* __restrict__ M64,
                                                      unsigned short* __restrict__ Ob) {
    __shared__ __align__(16) unsigned short Kls[64 * 64];
    __shared__ __align__(16) unsigned short Vls[64 * 64];

    const int tid  = threadIdx.x;
    const int wid  = tid >> 6, lane = tid & 63;
    const int hi   = lane >> 5, l31 = lane & 31, l7 = lane & 7;
    const int bid = blockIdx.x;
    const int bh  = (bid & 7) * 8 + (bid >> 7);
    const int qt  = (bid >> 3) & 15;
    const int b = bh >> 4, h = bh & 15;
    const int q0 = qt * 128;

    bf16x8 qB[4];
    {
        const unsigned short* qrow = Q + ((size_t)bh * SEQ + q0 + wid * 32 + l31) * HD + hi * 8;
#pragma unroll
        for (int ks = 0; ks < 4; ks++)
            qB[ks] = __builtin_bit_cast(bf16x8, *(const uint4*)(qrow + ks * 16));
    }

    f32x16 Oa[2];
    Oa[0] = (f32x16)0.0f;
    Oa[1] = (f32x16)0.0f;
    float ls = 0.0f;

    const unsigned long long* Mrow = M64 + b * (SEQ / 64);

    const int srow = lane >> 3;
    const int sgr  = ((lane & 7) ^ ((lane >> 3) & 7)) * 8;
    const unsigned short* Kg = K  + (size_t)bh * SEQ * HD;
    const unsigned short* Vg = Vt + (size_t)bh * HD * SEQ;
    const unsigned short* Kb0 = Kg + (size_t)(wid * 16 + srow) * HD + sgr;
    const unsigned short* Vb0 = Vg + (size_t)(wid * 16 + srow) * SEQ + sgr;

    for (int kt = 0; kt < SEQ / 64; kt++) {
        const int k0 = kt * 64;
#pragma unroll
        for (int j = 0; j < 2; j++) {
            __builtin_amdgcn_global_load_lds(
                (const __attribute__((address_space(1))) void*)(Kb0 + (size_t)(k0 + j * 8) * HD),
                (__attribute__((address_space(3))) void*)&Kls[(wid * 16 + j * 8) * 64], 16, 0, 0);
            __builtin_amdgcn_global_load_lds(
                (const __attribute__((address_space(1))) void*)(Vb0 + (size_t)(j * 8) * SEQ + k0),
                (__attribute__((address_space(3))) void*)&Vls[(wid * 16 + j * 8) * 64], 16, 0, 0);
        }
        unsigned long long mb = Mrow[kt];
        __syncthreads();

#pragma unroll
        for (int h2 = 0; h2 < 2; h2++) {
            bf16x8 kA[4];
#pragma unroll
            for (int ks = 0; ks < 4; ks++)
                kA[ks] = *(const bf16x8*)&Kls[(h2 * 32 + l31) * 64 + (((ks << 1) + hi) ^ l7) * 8];

            f32x16 st = (f32x16)0.0f;
            __builtin_amdgcn_s_setprio(1);
#pragma unroll
            for (int ks = 0; ks < 4; ks++)
                st = __builtin_amdgcn_mfma_f32_32x32x16_bf16(kA[ks], qB[ks], st, 0, 0, 0);
            __builtin_amdgcn_s_setprio(0);

            unsigned int mh = (unsigned int)(mb >> (h2 * 32));
            if (mh) {
#pragma unroll
                for (int r = 0; r < 16; r++) {
                    int kk = (r & 3) + ((r >> 2) << 3) + (hi << 2);
                    if ((mh >> kk) & 1u) st[r] = -1e9f;
                }
            }

            float p[16];
#pragma unroll
            for (int r = 0; r < 16; r++) p[r] = __builtin_amdgcn_exp2f(st[r]);
            float s01 = (p[0] + p[1]) + (p[2] + p[3]);
            float s23 = (p[4] + p[5]) + (p[6] + p[7]);
            float s45 = (p[8] + p[9]) + (p[10] + p[11]);
            float s67 = (p[12] + p[13]) + (p[14] + p[15]);
            ls += (s01 + s23) + (s45 + s67);

            unsigned int w000 = pack2bf_trunc(p[0],  p[1]);
            unsigned int w001 = pack2bf_trunc(p[2],  p[3]);
            unsigned int w010 = pack2bf_trunc(p[4],  p[5]);
            unsigned int w011 = pack2bf_trunc(p[6],  p[7]);
            unsigned int w100 = pack2bf_trunc(p[8],  p[9]);
            unsigned int w101 = pack2bf_trunc(p[10], p[11]);
            unsigned int w110 = pack2bf_trunc(p[12], p[13]);
            unsigned int w111 = pack2bf_trunc(p[14], p[15]);

            bf16x8 pB[2];
#pragma unroll
            for (int ks = 0; ks < 2; ks++) {
                unsigned int own0 = ks == 0 ? (hi ? w010 : w000) : (hi ? w110 : w100);
                unsigned int own1 = ks == 0 ? (hi ? w011 : w001) : (hi ? w111 : w101);
                unsigned int oth0 = ks == 0 ? (hi ? w000 : w010) : (hi ? w100 : w110);
                unsigned int oth1 = ks == 0 ? (hi ? w001 : w011) : (hi ? w101 : w111);
                unsigned int r0 = (unsigned int)__shfl_xor((int)oth0, 32);
                unsigned int r1 = (unsigned int)__shfl_xor((int)oth1, 32);
                uint4 pw;
                pw.x = hi ? r0 : own0;
                pw.y = hi ? r1 : own1;
                pw.z = hi ? own0 : r0;
                pw.w = hi ? own1 : r1;
                pB[ks] = __builtin_bit_cast(bf16x8, pw);
            }

            __builtin_amdgcn_s_setprio(1);
#pragma unroll
            for (int dt = 0; dt < 2; dt++)
#pragma unroll
                for (int kv = 0; kv < 2; kv++) {
                    bf16x8 vA = *(const bf16x8*)&Vls[(dt * 32 + l31) * 64 +
                                    (((h2 << 2) + (kv << 1) + hi) ^ l7) * 8];
                    Oa[dt] = __builtin_amdgcn_mfma_f32_32x32x16_bf16(vA, pB[kv], Oa[dt], 0, 0, 0);
                }
            __builtin_amdgcn_s_setprio(0);
        }
        __syncthreads();
    }

    float lsum = ls + __shfl_xor(ls, 32);
    float linv = 1.0f / lsum;

    const int s = q0 + wid * 32 + l31;
    unsigned short* orow = Ob + ((size_t)b * SEQ + s) * DIMN + h * HD + hi * 4;
#pragma unroll
    for (int dt = 0; dt < 2; dt++)
#pragma unroll
        for (int rq = 0; rq < 4; rq++) {
            uint2 w;
            w.x = pack2bf(Oa[dt][rq * 4 + 0] * linv, Oa[dt][rq * 4 + 1] * linv);
            w.y = pack2bf(Oa[dt][rq * 4 + 2] * linv, Oa[dt][rq * 4 + 3] * linv);
            *(uint2*)&orow[dt * 32 + rq * 8] = w;
        }
}

// ---------------------------------------------------------------- launch
extern "C" void kernel_launch(void* const* d_in, const int* in_sizes, int n_in,
                              void* d_out, int out_size, void* d_ws, size_t ws_size,
                              hipStream_t stream) {
    (void)in_sizes; (void)n_in; (void)out_size;
    const float* x  = (const float*)d_in[0];
    const unsigned char* mask = (const unsigned char*)d_in[1];
    const float* q_w = (const float*)d_in[2];
    const float* q_b = (const float*)d_in[3];
    const float* k_w = (const float*)d_in[4];
    const float* k_b = (const float*)d_in[5];
    const float* v_w = (const float*)d_in[6];
    const float* v_b = (const float*)d_in[7];
    const float* o_w = (const float*)d_in[8];
    const float* o_b = (const float*)d_in[9];
    float* out = (float*)d_out;

    // Workspace map (byte offsets):
    //   0   .. 16 MiB   xb  (bf16 x, reused as attn output Ob)
    //   16  .. 24 MiB   wq/wk/wv/wo (2 MiB each)
    //   24  .. 24.25    cosT/sinT (256 KiB)
    //   24.5            m64 (1 KiB)
    //   25  .. 41 MiB   Qb   (8M bf16 elements = 16 MiB)
    //   41  .. 57 MiB   Kb
    //   57  .. 73 MiB   Vtb
    //   73  .. 137 MiB  Opart (2048 parts x 128 q x 64 d f32 = 64 MiB)
    //   137 .. 138 MiB  Lpart (2048 x 128 f32 = 1 MiB)
    char* w = (char*)d_ws;
    unsigned short* xb = (unsigned short*)w;
    unsigned short* wq = (unsigned short*)(w + (16u << 20));
    unsigned short* wk = wq + (1u << 20);
    unsigned short* wv = wk + (1u << 20);
    unsigned short* wo = wv + (1u << 20);
    float* cosT = (float*)(w + (24u << 20));
    float* sinT = cosT + SEQ * 32;
    unsigned long long* m64 = (unsigned long long*)(w + (24u << 20) + (1u << 19));
    unsigned short* Qb  = (unsigned short*)(w + (25u << 20));
    unsigned short* Kb  = Qb + (8u << 20);          // +16 MiB (elements!)
    unsigned short* Vtb = Kb + (8u << 20);          // +16 MiB
    unsigned short* Ob  = xb;                       // reuse x's slot
    float* Opart = (float*)(w + (73u << 20));       // 64 MiB
    float* Lpart = (float*)(w + (137u << 20));      // 1 MiB

    prologue_kernel<<<dim3(6401), 256, 0, stream>>>(x, q_w, k_w, v_w, o_w,
                                                    xb, wq, wk, wv, wo,
                                                    cosT, sinT, mask, m64);

    gemm_qkvt<<<dim3(24, 64), 256, 0, stream>>>(xb, wq, wk, wv, q_b, k_b, v_b,
                                                Qb, Kb, Vtb, cosT, sinT);

    if (ws_size >= (138ull << 20)) {
        attn_part<<<dim3(2048), 256, 0, stream>>>(Qb, Kb, Vtb, m64, Opart, Lpart);
        attn_norm<<<dim3(1024), 256, 0, stream>>>(Opart, Lpart, Ob);
    } else {
        attn_kernel<<<dim3(1024), 256, 0, stream>>>(Qb, Kb, Vtb, m64, Ob);
    }

    gemm_bt<<<dim3(DIMN / 128, MROWS / 128), 256, 0, stream>>>(Ob, wo, o_b, out);
}

// Round 11
// 306.729 us; speedup vs baseline: 2.3312x; 2.3312x over previous
//
#include <hip/hip_runtime.h>
#include <stdint.h>

#define SEQ   2048
#define BATCH 4
#define NH    16
#define HD    64
#define DIMN  1024
#define MROWS (BATCH*SEQ)   // 8192

typedef __attribute__((ext_vector_type(8)))  short          bf16x8;
typedef __attribute__((ext_vector_type(8)))  unsigned short ushort8;
typedef __attribute__((ext_vector_type(4)))  float          f32x4;
typedef __attribute__((ext_vector_type(16))) float          f32x16;

static __device__ __forceinline__ unsigned short f2bf(float f) {
    unsigned int u = __builtin_bit_cast(unsigned int, f);
    u += 0x7fffu + ((u >> 16) & 1u);          // RNE
    return (unsigned short)(u >> 16);
}
// RNE-ish (round-half-up) pack: 3 ops
static __device__ __forceinline__ unsigned int pack2bf(float lo, float hi) {
    unsigned int a = __builtin_bit_cast(unsigned int, lo) + 0x8000u;
    unsigned int b = __builtin_bit_cast(unsigned int, hi) + 0x8000u;
    return __builtin_amdgcn_perm(b, a, 0x07060302u);
}
// truncating pack: 1 op (P in [0,1], rel err <= 2^-8, fine for softmax weights)
static __device__ __forceinline__ unsigned int pack2bf_trunc(float lo, float hi) {
    return __builtin_amdgcn_perm(__builtin_bit_cast(unsigned int, hi),
                                 __builtin_bit_cast(unsigned int, lo), 0x07060302u);
}

// ---------------------------------------------------------------- fused prologue
__global__ __launch_bounds__(256) void prologue_kernel(
        const float* __restrict__ x,
        const float* __restrict__ qw, const float* __restrict__ kw,
        const float* __restrict__ vw, const float* __restrict__ ow,
        unsigned short* __restrict__ xb,
        unsigned short* __restrict__ wq, unsigned short* __restrict__ wk,
        unsigned short* __restrict__ wv, unsigned short* __restrict__ wo,
        float* __restrict__ cosT, float* __restrict__ sinT,
        const unsigned char* __restrict__ mask, unsigned long long* __restrict__ m64) {
    const int bx = blockIdx.x, tid = threadIdx.x;
    if (bx < 4096 + 2048) {
        const float* s; unsigned short* d; int i;
        if (bx < 4096) { s = x; d = xb; i = bx * 2048 + tid * 8; }
        else {
            int wb = bx - 4096;
            int wsel = wb >> 9;
            s = wsel == 0 ? qw : (wsel == 1 ? kw : (wsel == 2 ? vw : ow));
            d = wsel == 0 ? wq : (wsel == 1 ? wk : (wsel == 2 ? wv : wo));
            i = (wb & 511) * 2048 + tid * 8;
        }
        float4 a = *(const float4*)(s + i);
        float4 b = *(const float4*)(s + i + 4);
        ushort8 o;
        o[0]=f2bf(a.x); o[1]=f2bf(a.y); o[2]=f2bf(a.z); o[3]=f2bf(a.w);
        o[4]=f2bf(b.x); o[5]=f2bf(b.y); o[6]=f2bf(b.z); o[7]=f2bf(b.w);
        *(ushort8*)(d + i) = o;
    } else if (bx < 6400) {
        int idx = (bx - 6144) * 256 + tid;        // SEQ*32
        int s = idx >> 5, j = idx & 31;
        float t = (float)(2 * j) / 64.0f;
        float freq = 1.0f / powf(10000.0f, t);
        float ang  = (float)s * freq;
        cosT[idx] = cosf(ang);
        sinT[idx] = sinf(ang);
    } else {
        if (tid < 128) {
            int b = tid >> 5, kt = tid & 31;
            const unsigned char* p = mask + b * SEQ + kt * 64;
            unsigned long long v = 0;
            for (int j = 0; j < 64; j++) v |= (unsigned long long)(p[j] != 0) << j;
            m64[tid] = v;
        }
    }
}

// ---------------------------------------------------------------- fused Q,K,V^T GEMM
// (R6 version) LDS double-buffer + early stage; ONE barrier per 32-step;
// chunk XOR swizzle.
__global__ __launch_bounds__(256) void gemm_qkvt(const unsigned short* __restrict__ X,
        const unsigned short* __restrict__ Wq, const unsigned short* __restrict__ Wk,
        const unsigned short* __restrict__ Wv,
        const float* __restrict__ bq, const float* __restrict__ bk, const float* __restrict__ bv,
        unsigned short* __restrict__ Qo, unsigned short* __restrict__ Ko, unsigned short* __restrict__ Vto,
        const float* __restrict__ cosT, const float* __restrict__ sinT) {
    __shared__ __align__(16) unsigned short As0[128 * 32];
    __shared__ __align__(16) unsigned short Bs0[128 * 32];
    __shared__ __align__(16) unsigned short As1[128 * 32];
    __shared__ __align__(16) unsigned short Bs1[128 * 32];
    const int which = blockIdx.x >> 3;
    const int tid  = threadIdx.x;
    const int wid  = tid >> 6, lane = tid & 63;
    const int quad = lane >> 4, l15 = lane & 15;
    const int wm   = wid >> 1,  wn  = wid & 1;

    const unsigned short *Ag, *Bg;
    int m0, n0;
    if (which < 2) {
        m0 = blockIdx.y * 128;                 // token rows
        n0 = (blockIdx.x & 7) * 128;           // embed cols
        Ag = X;  Bg = which == 0 ? Wq : Wk;
    } else {
        m0 = (blockIdx.x & 7) * 128;           // e rows
        n0 = blockIdx.y * 128;                 // token rows
        Ag = Wv; Bg = X;
    }

    f32x4 acc[4][4];
#pragma unroll
    for (int i = 0; i < 4; i++)
#pragma unroll
        for (int j = 0; j < 4; j++) acc[i][j] = (f32x4)0.0f;

    const int rb = wid * 32 + (lane >> 2);
    const int cb = (((lane & 3) ^ ((lane >> 3) & 3)) * 8);
    const int rq = (quad ^ ((l15 >> 1) & 3)) * 8;

#define GSTAGE(BA, BB, KK) do {                                                             \
    _Pragma("unroll")                                                                       \
    for (int i_ = 0; i_ < 2; i_++) {                                                        \
        const unsigned short* ga_ = Ag + (size_t)(m0 + rb + i_ * 16) * DIMN + (KK) + cb;    \
        __builtin_amdgcn_global_load_lds((const __attribute__((address_space(1))) void*)ga_,\
            (__attribute__((address_space(3))) void*)&BA[(wid * 32 + i_ * 16) * 32], 16, 0, 0);\
        const unsigned short* gb_ = Bg + (size_t)(n0 + rb + i_ * 16) * DIMN + (KK) + cb;    \
        __builtin_amdgcn_global_load_lds((const __attribute__((address_space(1))) void*)gb_,\
            (__attribute__((address_space(3))) void*)&BB[(wid * 32 + i_ * 16) * 32], 16, 0, 0);\
    } } while (0)

#define GCOMP(BA, BB) do {                                                                  \
    bf16x8 af_[4], bf_[4];                                                                  \
    _Pragma("unroll")                                                                       \
    for (int f_ = 0; f_ < 4; f_++) af_[f_] = *(const bf16x8*)&BA[(wm * 64 + f_ * 16 + l15) * 32 + rq]; \
    _Pragma("unroll")                                                                       \
    for (int f_ = 0; f_ < 4; f_++) bf_[f_] = *(const bf16x8*)&BB[(wn * 64 + f_ * 16 + l15) * 32 + rq]; \
    _Pragma("unroll")                                                                       \
    for (int fm_ = 0; fm_ < 4; fm_++)                                                       \
        _Pragma("unroll")                                                                   \
        for (int fn_ = 0; fn_ < 4; fn_++)                                                   \
            acc[fm_][fn_] = __builtin_amdgcn_mfma_f32_16x16x32_bf16(af_[fm_], bf_[fn_], acc[fm_][fn_], 0, 0, 0); \
    } while (0)

    GSTAGE(As0, Bs0, 0);
    for (int k0 = 0; k0 < DIMN; k0 += 64) {
        __syncthreads();                           // As0/Bs0 ready
        GSTAGE(As1, Bs1, k0 + 32);                 // issue next into other buffer
        GCOMP(As0, Bs0);
        __syncthreads();                           // As1/Bs1 ready
        if (k0 + 64 < DIMN) GSTAGE(As0, Bs0, k0 + 64);
        GCOMP(As1, Bs1);
    }

    if (which < 2) {                            // Q or K: +bias, scale, RoPE, [B,H,S,D]
        const float* bias   = which == 0 ? bq : bk;
        unsigned short* Out = which == 0 ? Qo : Ko;
        const float scale = which == 0 ? 0.18033688011112042f : 1.0f;  // 0.125*log2e
        float bv4[4];
#pragma unroll
        for (int fn = 0; fn < 4; fn++) bv4[fn] = bias[n0 + wn * 64 + fn * 16 + l15];
        const int h = (n0 >> 6) + wn;
#pragma unroll
        for (int fm = 0; fm < 4; fm++)
#pragma unroll
            for (int r = 0; r < 4; r++) {
                int mrow = m0 + wm * 64 + fm * 16 + quad * 4 + r;
                int b = mrow >> 11, s = mrow & (SEQ - 1);
                unsigned short* orow = Out + ((size_t)(b * NH + h) * SEQ + s) * HD;
                float v0 = (acc[fm][0][r] + bv4[0]) * scale;
                float v1 = (acc[fm][1][r] + bv4[1]) * scale;
                float v2 = (acc[fm][2][r] + bv4[2]) * scale;
                float v3 = (acc[fm][3][r] + bv4[3]) * scale;
                int d0 = l15, d1 = 16 + l15;
                float c0 = cosT[s * 32 + d0], s0 = sinT[s * 32 + d0];
                float c1 = cosT[s * 32 + d1], s1 = sinT[s * 32 + d1];
                orow[d0]      = f2bf(v0 * c0 - v2 * s0);
                orow[d0 + 32] = f2bf(v0 * s0 + v2 * c0);
                orow[d1]      = f2bf(v1 * c1 - v3 * s1);
                orow[d1 + 32] = f2bf(v1 * s1 + v3 * c1);
            }
    } else {                                    // V^T: [B,H,D,S]
        float4 bb[4];
#pragma unroll
        for (int fm = 0; fm < 4; fm++)
            bb[fm] = *(const float4*)&bv[m0 + wm * 64 + fm * 16 + quad * 4];
        const int b     = n0 >> 11;
        const int sbase = (n0 & (SEQ - 1)) + wn * 64 + l15;
#pragma unroll
        for (int fm = 0; fm < 4; fm++)
#pragma unroll
            for (int r = 0; r < 4; r++) {
                int e = m0 + wm * 64 + fm * 16 + quad * 4 + r;
                float bval = r == 0 ? bb[fm].x : (r == 1 ? bb[fm].y : (r == 2 ? bb[fm].z : bb[fm].w));
                unsigned short* row = Vto + ((size_t)(b * NH + (e >> 6)) * HD + (e & 63)) * SEQ + sbase;
#pragma unroll
                for (int fn = 0; fn < 4; fn++)
                    row[fn * 16] = f2bf(acc[fm][fn][r] + bval);
            }
    }
#undef GSTAGE
#undef GCOMP
}

// ---------------------------------------------------------------- output-proj GEMM (fp32 out)
__global__ __launch_bounds__(256) void gemm_bt(const unsigned short* __restrict__ A,
                                               const unsigned short* __restrict__ W,
                                               const float* __restrict__ bias,
                                               float* __restrict__ out) {
    __shared__ __align__(16) unsigned short As0[128 * 32];
    __shared__ __align__(16) unsigned short Bs0[128 * 32];
    __shared__ __align__(16) unsigned short As1[128 * 32];
    __shared__ __align__(16) unsigned short Bs1[128 * 32];
    const int tid  = threadIdx.x;
    const int wid  = tid >> 6, lane = tid & 63;
    const int quad = lane >> 4, l15 = lane & 15;
    const int wm   = wid >> 1,  wn  = wid & 1;
    const int m0   = blockIdx.y * 128, n0 = blockIdx.x * 128;

    f32x4 acc[4][4];
#pragma unroll
    for (int i = 0; i < 4; i++)
#pragma unroll
        for (int j = 0; j < 4; j++) acc[i][j] = (f32x4)0.0f;

    const int rb = wid * 32 + (lane >> 2);
    const int cb = (((lane & 3) ^ ((lane >> 3) & 3)) * 8);
    const int rq = (quad ^ ((l15 >> 1) & 3)) * 8;

#define GSTAGE(BA, BB, KK) do {                                                             \
    _Pragma("unroll")                                                                       \
    for (int i_ = 0; i_ < 2; i_++) {                                                        \
        const unsigned short* ga_ = A + (size_t)(m0 + rb + i_ * 16) * DIMN + (KK) + cb;     \
        __builtin_amdgcn_global_load_lds((const __attribute__((address_space(1))) void*)ga_,\
            (__attribute__((address_space(3))) void*)&BA[(wid * 32 + i_ * 16) * 32], 16, 0, 0);\
        const unsigned short* gb_ = W + (size_t)(n0 + rb + i_ * 16) * DIMN + (KK) + cb;     \
        __builtin_amdgcn_global_load_lds((const __attribute__((address_space(1))) void*)gb_,\
            (__attribute__((address_space(3))) void*)&BB[(wid * 32 + i_ * 16) * 32], 16, 0, 0);\
    } } while (0)

#define GCOMP(BA, BB) do {                                                                  \
    bf16x8 af_[4], bf_[4];                                                                  \
    _Pragma("unroll")                                                                       \
    for (int f_ = 0; f_ < 4; f_++) af_[f_] = *(const bf16x8*)&BA[(wm * 64 + f_ * 16 + l15) * 32 + rq]; \
    _Pragma("unroll")                                                                       \
    for (int f_ = 0; f_ < 4; f_++) bf_[f_] = *(const bf16x8*)&BB[(wn * 64 + f_ * 16 + l15) * 32 + rq]; \
    _Pragma("unroll")                                                                       \
    for (int fm_ = 0; fm_ < 4; fm_++)                                                       \
        _Pragma("unroll")                                                                   \
        for (int fn_ = 0; fn_ < 4; fn_++)                                                   \
            acc[fm_][fn_] = __builtin_amdgcn_mfma_f32_16x16x32_bf16(af_[fm_], bf_[fn_], acc[fm_][fn_], 0, 0, 0); \
    } while (0)

    GSTAGE(As0, Bs0, 0);
    for (int k0 = 0; k0 < DIMN; k0 += 64) {
        __syncthreads();
        GSTAGE(As1, Bs1, k0 + 32);
        GCOMP(As0, Bs0);
        __syncthreads();
        if (k0 + 64 < DIMN) GSTAGE(As0, Bs0, k0 + 64);
        GCOMP(As1, Bs1);
    }

    float bv4[4];
#pragma unroll
    for (int fn = 0; fn < 4; fn++) bv4[fn] = bias[n0 + wn * 64 + fn * 16 + l15];
#pragma unroll
    for (int fm = 0; fm < 4; fm++)
#pragma unroll
        for (int r = 0; r < 4; r++) {
            int mrow = m0 + wm * 64 + fm * 16 + quad * 4 + r;
            float* orow = out + (size_t)mrow * DIMN + n0 + wn * 64;
#pragma unroll
            for (int fn = 0; fn < 4; fn++) orow[fn * 16 + l15] = acc[fm][fn][r] + bv4[fn];
        }
#undef GSTAGE
#undef GCOMP
}

// ---------------------------------------------------------------- flash attention v15 (split-K stage 1)
// R10 post-mortem: split-K CORRECT and occupancy jumped to 87%, but
// launch_bounds(256,8) capped the unified reg budget at 512/8=64 -> compiler
// split 32 arch + 32 acc (VGPR_Count=32) and spilled: FETCH 1.23 GB / WRITE
// 982 MB of scratch traffic, MfmaUtil 5.7%. R11 fix: bound back to (256,4)
// (budget 128). v13's identical core compiles to exactly 64 total regs at
// that bound, and at <=64 regs the HARDWARE schedules 8 waves/SIMD anyway
// (m69) -- the bound constrains the allocator, not the scheduler. Grid 2048
// + 64 VGPR => spill-free AND high occupancy.
__global__ __launch_bounds__(256, 4) void attn_part(const unsigned short* __restrict__ Q,
                                                    const unsigned short* __restrict__ K,
                                                    const unsigned short* __restrict__ Vt,
                                                    const unsigned long long* __restrict__ M64,
                                                    float* __restrict__ Opart,
                                                    float* __restrict__ Lpart) {
    __shared__ __align__(16) unsigned short Kls[64 * 64];   // 8 KiB [token][k]
    __shared__ __align__(16) unsigned short Vls[64 * 64];   // 8 KiB [d][token]

    const int tid  = threadIdx.x;
    const int wid  = tid >> 6, lane = tid & 63;
    const int hi   = lane >> 5, l31 = lane & 31, l7 = lane & 7;
    // bid = xcd + 8*(sh + 2*qt) + 256*hi8; bh = xcd*8 + hi8 -> all 32 blocks
    // of a (b,h) stay on one XCD (K/V L2-resident).
    const int bid = blockIdx.x;
    const int bh  = (bid & 7) * 8 + (bid >> 8);
    const int mid = (bid >> 3) & 31;
    const int qt  = mid >> 1, sh = mid & 1;
    const int b = bh >> 4;
    const int q0 = qt * 128;

    bf16x8 qB[4];
    {
        const unsigned short* qrow = Q + ((size_t)bh * SEQ + q0 + wid * 32 + l31) * HD + hi * 8;
#pragma unroll
        for (int ks = 0; ks < 4; ks++)
            qB[ks] = __builtin_bit_cast(bf16x8, *(const uint4*)(qrow + ks * 16));
    }

    f32x16 Oa[2];                 // O^T tiles: d = dt*32 + (r&3)+8*(r>>2)+4*hi, q = l31
    Oa[0] = (f32x16)0.0f;
    Oa[1] = (f32x16)0.0f;
    float ls = 0.0f;

    const unsigned long long* Mrow = M64 + b * (SEQ / 64);

    const int srow = lane >> 3;
    const int sgr  = ((lane & 7) ^ ((lane >> 3) & 7)) * 8;
    const unsigned short* Kg = K  + (size_t)bh * SEQ * HD;
    const unsigned short* Vg = Vt + (size_t)bh * HD * SEQ;
    const unsigned short* Kb0 = Kg + (size_t)(wid * 16 + srow) * HD + sgr;
    const unsigned short* Vb0 = Vg + (size_t)(wid * 16 + srow) * SEQ + sgr;

    for (int kt = sh * 16; kt < sh * 16 + 16; kt++) {
        const int k0 = kt * 64;
#pragma unroll
        for (int j = 0; j < 2; j++) {
            __builtin_amdgcn_global_load_lds(
                (const __attribute__((address_space(1))) void*)(Kb0 + (size_t)(k0 + j * 8) * HD),
                (__attribute__((address_space(3))) void*)&Kls[(wid * 16 + j * 8) * 64], 16, 0, 0);
            __builtin_amdgcn_global_load_lds(
                (const __attribute__((address_space(1))) void*)(Vb0 + (size_t)(j * 8) * SEQ + k0),
                (__attribute__((address_space(3))) void*)&Vls[(wid * 16 + j * 8) * 64], 16, 0, 0);
        }
        unsigned long long mb = Mrow[kt];
        __syncthreads();

#pragma unroll
        for (int h2 = 0; h2 < 2; h2++) {
            bf16x8 kA[4];
#pragma unroll
            for (int ks = 0; ks < 4; ks++)
                kA[ks] = *(const bf16x8*)&Kls[(h2 * 32 + l31) * 64 + (((ks << 1) + hi) ^ l7) * 8];

            f32x16 st = (f32x16)0.0f;
            __builtin_amdgcn_s_setprio(1);
#pragma unroll
            for (int ks = 0; ks < 4; ks++)
                st = __builtin_amdgcn_mfma_f32_32x32x16_bf16(kA[ks], qB[ks], st, 0, 0, 0);
            __builtin_amdgcn_s_setprio(0);

            unsigned int mh = (unsigned int)(mb >> (h2 * 32));
            if (mh) {
#pragma unroll
                for (int r = 0; r < 16; r++) {
                    int kk = (r & 3) + ((r >> 2) << 3) + (hi << 2);
                    if ((mh >> kk) & 1u) st[r] = -1e9f;
                }
            }

            float p[16];
#pragma unroll
            for (int r = 0; r < 16; r++) p[r] = __builtin_amdgcn_exp2f(st[r]);
            float s01 = (p[0] + p[1]) + (p[2] + p[3]);
            float s23 = (p[4] + p[5]) + (p[6] + p[7]);
            float s45 = (p[8] + p[9]) + (p[10] + p[11]);
            float s67 = (p[12] + p[13]) + (p[14] + p[15]);
            ls += (s01 + s23) + (s45 + s67);

            unsigned int w000 = pack2bf_trunc(p[0],  p[1]);
            unsigned int w001 = pack2bf_trunc(p[2],  p[3]);
            unsigned int w010 = pack2bf_trunc(p[4],  p[5]);
            unsigned int w011 = pack2bf_trunc(p[6],  p[7]);
            unsigned int w100 = pack2bf_trunc(p[8],  p[9]);
            unsigned int w101 = pack2bf_trunc(p[10], p[11]);
            unsigned int w110 = pack2bf_trunc(p[12], p[13]);
            unsigned int w111 = pack2bf_trunc(p[14], p[15]);

            bf16x8 pB[2];
#pragma unroll
            for (int ks = 0; ks < 2; ks++) {
                unsigned int own0 = ks == 0 ? (hi ? w010 : w000) : (hi ? w110 : w100);
                unsigned int own1 = ks == 0 ? (hi ? w011 : w001) : (hi ? w111 : w101);
                unsigned int oth0 = ks == 0 ? (hi ? w000 : w010) : (hi ? w100 : w110);
                unsigned int oth1 = ks == 0 ? (hi ? w001 : w011) : (hi ? w101 : w111);
                unsigned int r0 = (unsigned int)__shfl_xor((int)oth0, 32);
                unsigned int r1 = (unsigned int)__shfl_xor((int)oth1, 32);
                uint4 pw;
                pw.x = hi ? r0 : own0;
                pw.y = hi ? r1 : own1;
                pw.z = hi ? own0 : r0;
                pw.w = hi ? own1 : r1;
                pB[ks] = __builtin_bit_cast(bf16x8, pw);
            }

            __builtin_amdgcn_s_setprio(1);
#pragma unroll
            for (int dt = 0; dt < 2; dt++)
#pragma unroll
                for (int kv = 0; kv < 2; kv++) {
                    bf16x8 vA = *(const bf16x8*)&Vls[(dt * 32 + l31) * 64 +
                                    (((h2 << 2) + (kv << 1) + hi) ^ l7) * 8];
                    Oa[dt] = __builtin_amdgcn_mfma_f32_32x32x16_bf16(vA, pB[kv], Oa[dt], 0, 0, 0);
                }
            __builtin_amdgcn_s_setprio(0);
        }
        __syncthreads();
    }

    // partial-l: reduce the two hi-halves (full 1024-key sum for q=l31)
    float lsum = ls + __shfl_xor(ls, 32);
    const int ql = wid * 32 + l31;                 // block-local q row 0..127
    const size_t part = (size_t)((bh * 16 + qt) * 2 + sh);
    if (hi == 0) Lpart[part * 128 + ql] = lsum;

    // partial-O: [128 q][64 d] f32 per (bh,qt,sh)
    float* Op = Opart + part * (128 * 64) + (size_t)ql * 64;
#pragma unroll
    for (int dt = 0; dt < 2; dt++)
#pragma unroll
        for (int rg = 0; rg < 4; rg++) {
            float4 v;
            v.x = Oa[dt][rg * 4 + 0];
            v.y = Oa[dt][rg * 4 + 1];
            v.z = Oa[dt][rg * 4 + 2];
            v.w = Oa[dt][rg * 4 + 3];
            *(float4*)(Op + dt * 32 + rg * 8 + hi * 4) = v;
        }
}

// ---------------------------------------------------------------- attn stage 2: combine + normalize
__global__ __launch_bounds__(256) void attn_norm(const float* __restrict__ Opart,
                                                 const float* __restrict__ Lpart,
                                                 unsigned short* __restrict__ Ob) {
    const int bq = blockIdx.x;            // bh*16 + qt
    const int bh = bq >> 4, qt = bq & 15;
    const int b = bh >> 4, h = bh & 15;
    const int tid = threadIdx.x;
    const int q = tid >> 1, dh = (tid & 1) * 32;

    const float l0 = Lpart[(size_t)(bq * 2 + 0) * 128 + q];
    const float l1 = Lpart[(size_t)(bq * 2 + 1) * 128 + q];
    const float linv = 1.0f / (l0 + l1);

    const float* O0 = Opart + (size_t)(bq * 2 + 0) * (128 * 64) + (size_t)q * 64 + dh;
    const float* O1 = O0 + 128 * 64;

    const int s = qt * 128 + q;
    unsigned short* orow = Ob + ((size_t)b * SEQ + s) * DIMN + h * HD + dh;
#pragma unroll
    for (int g = 0; g < 4; g++) {
        float4 a0 = *(const float4*)(O0 + g * 8);
        float4 a1 = *(const float4*)(O0 + g * 8 + 4);
        float4 c0 = *(const float4*)(O1 + g * 8);
        float4 c1 = *(const float4*)(O1 + g * 8 + 4);
        uint4 st;
        st.x = pack2bf((a0.x + c0.x) * linv, (a0.y + c0.y) * linv);
        st.y = pack2bf((a0.z + c0.z) * linv, (a0.w + c0.w) * linv);
        st.z = pack2bf((a1.x + c1.x) * linv, (a1.y + c1.y) * linv);
        st.w = pack2bf((a1.z + c1.z) * linv, (a1.w + c1.w) * linv);
        *(uint4*)(orow + g * 8) = st;
    }
}

// ---------------------------------------------------------------- flash attention v13 (fallback)
// Used when workspace is too small for the split-K partials.
__global__ __launch_bounds__(256, 4) void attn_kernel(const unsigned short* __restrict__ Q,
                                                      const unsigned short* __restrict__ K,
                                                      const unsigned short* __restrict__ Vt,
                                                      const unsigned long long* __restrict__ M64,
                                                      unsigned short* __restrict__ Ob) {
    __shared__ __align__(16) unsigned short Kls[64 * 64];
    __shared__ __align__(16) unsigned short Vls[64 * 64];

    const int tid  = threadIdx.x;
    const int wid  = tid >> 6, lane = tid & 63;
    const int hi   = lane >> 5, l31 = lane & 31, l7 = lane & 7;
    const int bid = blockIdx.x;
    const int bh  = (bid & 7) * 8 + (bid >> 7);
    const int qt  = (bid >> 3) & 15;
    const int b = bh >> 4, h = bh & 15;
    const int q0 = qt * 128;

    bf16x8 qB[4];
    {
        const unsigned short* qrow = Q + ((size_t)bh * SEQ + q0 + wid * 32 + l31) * HD + hi * 8;
#pragma unroll
        for (int ks = 0; ks < 4; ks++)
            qB[ks] = __builtin_bit_cast(bf16x8, *(const uint4*)(qrow + ks * 16));
    }

    f32x16 Oa[2];
    Oa[0] = (f32x16)0.0f;
    Oa[1] = (f32x16)0.0f;
    float ls = 0.0f;

    const unsigned long long* Mrow = M64 + b * (SEQ / 64);

    const int srow = lane >> 3;
    const int sgr  = ((lane & 7) ^ ((lane >> 3) & 7)) * 8;
    const unsigned short* Kg = K  + (size_t)bh * SEQ * HD;
    const unsigned short* Vg = Vt + (size_t)bh * HD * SEQ;
    const unsigned short* Kb0 = Kg + (size_t)(wid * 16 + srow) * HD + sgr;
    const unsigned short* Vb0 = Vg + (size_t)(wid * 16 + srow) * SEQ + sgr;

    for (int kt = 0; kt < SEQ / 64; kt++) {
        const int k0 = kt * 64;
#pragma unroll
        for (int j = 0; j < 2; j++) {
            __builtin_amdgcn_global_load_lds(
                (const __attribute__((address_space(1))) void*)(Kb0 + (size_t)(k0 + j * 8) * HD),
                (__attribute__((address_space(3))) void*)&Kls[(wid * 16 + j * 8) * 64], 16, 0, 0);
            __builtin_amdgcn_global_load_lds(
                (const __attribute__((address_space(1))) void*)(Vb0 + (size_t)(j * 8) * SEQ + k0),
                (__attribute__((address_space(3))) void*)&Vls[(wid * 16 + j * 8) * 64], 16, 0, 0);
        }
        unsigned long long mb = Mrow[kt];
        __syncthreads();

#pragma unroll
        for (int h2 = 0; h2 < 2; h2++) {
            bf16x8 kA[4];
#pragma unroll
            for (int ks = 0; ks < 4; ks++)
                kA[ks] = *(const bf16x8*)&Kls[(h2 * 32 + l31) * 64 + (((ks << 1) + hi) ^ l7) * 8];

            f32x16 st = (f32x16)0.0f;
            __builtin_amdgcn_s_setprio(1);
#pragma unroll
            for (int ks = 0; ks < 4; ks++)
                st = __builtin_amdgcn_mfma_f32_32x32x16_bf16(kA[ks], qB[ks], st, 0, 0, 0);
            __builtin_amdgcn_s_setprio(0);

            unsigned int mh = (unsigned int)(mb >> (h2 * 32));
            if (mh) {
#pragma unroll
                for (int r = 0; r < 16; r++) {
                    int kk = (r & 3) + ((r >> 2) << 3) + (hi << 2);
                    if ((mh >> kk) & 1u) st[r] = -1e9f;
                }
            }

            float p[16];
#pragma unroll
            for (int r = 0; r < 16; r++) p[r] = __builtin_amdgcn_exp2f(st[r]);
            float s01 = (p[0] + p[1]) + (p[2] + p[3]);
            float s23 = (p[4] + p[5]) + (p[6] + p[7]);
            float s45 = (p[8] + p[9]) + (p[10] + p[11]);
            float s67 = (p[12] + p[13]) + (p[14] + p[15]);
            ls += (s01 + s23) + (s45 + s67);

            unsigned int w000 = pack2bf_trunc(p[0],  p[1]);
            unsigned int w001 = pack2bf_trunc(p[2],  p[3]);
            unsigned int w010 = pack2bf_trunc(p[4],  p[5]);
            unsigned int w011 = pack2bf_trunc(p[6],  p[7]);
            unsigned int w100 = pack2bf_trunc(p[8],  p[9]);
            unsigned int w101 = pack2bf_trunc(p[10], p[11]);
            unsigned int w110 = pack2bf_trunc(p[12], p[13]);
            unsigned int w111 = pack2bf_trunc(p[14], p[15]);

            bf16x8 pB[2];
#pragma unroll
            for (int ks = 0; ks < 2; ks++) {
                unsigned int own0 = ks == 0 ? (hi ? w010 : w000) : (hi ? w110 : w100);
                unsigned int own1 = ks == 0 ? (hi ? w011 : w001) : (hi ? w111 : w101);
                unsigned int oth0 = ks == 0 ? (hi ? w000 : w010) : (hi ? w100 : w110);
                unsigned int oth1 = ks == 0 ? (hi ? w001 : w011) : (hi ? w101 : w111);
                unsigned int r0 = (unsigned int)__shfl_xor((int)oth0, 32);
                unsigned int r1 = (unsigned int)__shfl_xor((int)oth1, 32);
                uint4 pw;
                pw.x = hi ? r0 : own0;
                pw.y = hi ? r1 : own1;
                pw.z = hi ? own0 : r0;
                pw.w = hi ? own1 : r1;
                pB[ks] = __builtin_bit_cast(bf16x8, pw);
            }

            __builtin_amdgcn_s_setprio(1);
#pragma unroll
            for (int dt = 0; dt < 2; dt++)
#pragma unroll
                for (int kv = 0; kv < 2; kv++) {
                    bf16x8 vA = *(const bf16x8*)&Vls[(dt * 32 + l31) * 64 +
                                    (((h2 << 2) + (kv << 1) + hi) ^ l7) * 8];
                    Oa[dt] = __builtin_amdgcn_mfma_f32_32x32x16_bf16(vA, pB[kv], Oa[dt], 0, 0, 0);
                }
            __builtin_amdgcn_s_setprio(0);
        }
        __syncthreads();
    }

    float lsum = ls + __shfl_xor(ls, 32);
    float linv = 1.0f / lsum;

    const int s = q0 + wid * 32 + l31;
    unsigned short* orow = Ob + ((size_t)b * SEQ + s) * DIMN + h * HD + hi * 4;
#pragma unroll
    for (int dt = 0; dt < 2; dt++)
#pragma unroll
        for (int rq = 0; rq < 4; rq++) {
            uint2 w;
            w.x = pack2bf(Oa[dt][rq * 4 + 0] * linv, Oa[dt][rq * 4 + 1] * linv);
            w.y = pack2bf(Oa[dt][rq * 4 + 2] * linv, Oa[dt][rq * 4 + 3] * linv);
            *(uint2*)&orow[dt * 32 + rq * 8] = w;
        }
}

// ---------------------------------------------------------------- launch
extern "C" void kernel_launch(void* const* d_in, const int* in_sizes, int n_in,
                              void* d_out, int out_size, void* d_ws, size_t ws_size,
                              hipStream_t stream) {
    (void)in_sizes; (void)n_in; (void)out_size;
    const float* x  = (const float*)d_in[0];
    const unsigned char* mask = (const unsigned char*)d_in[1];
    const float* q_w = (const float*)d_in[2];
    const float* q_b = (const float*)d_in[3];
    const float* k_w = (const float*)d_in[4];
    const float* k_b = (const float*)d_in[5];
    const float* v_w = (const float*)d_in[6];
    const float* v_b = (const float*)d_in[7];
    const float* o_w = (const float*)d_in[8];
    const float* o_b = (const float*)d_in[9];
    float* out = (float*)d_out;

    // Workspace map (byte offsets):
    //   0   .. 16 MiB   xb  (bf16 x, reused as attn output Ob)
    //   16  .. 24 MiB   wq/wk/wv/wo (2 MiB each)
    //   24  .. 24.25    cosT/sinT (256 KiB)
    //   24.5            m64 (1 KiB)
    //   25  .. 41 MiB   Qb   (8M bf16 elements = 16 MiB)
    //   41  .. 57 MiB   Kb
    //   57  .. 73 MiB   Vtb
    //   73  .. 137 MiB  Opart (2048 parts x 128 q x 64 d f32 = 64 MiB)
    //   137 .. 138 MiB  Lpart (2048 x 128 f32 = 1 MiB)
    char* w = (char*)d_ws;
    unsigned short* xb = (unsigned short*)w;
    unsigned short* wq = (unsigned short*)(w + (16u << 20));
    unsigned short* wk = wq + (1u << 20);
    unsigned short* wv = wk + (1u << 20);
    unsigned short* wo = wv + (1u << 20);
    float* cosT = (float*)(w + (24u << 20));
    float* sinT = cosT + SEQ * 32;
    unsigned long long* m64 = (unsigned long long*)(w + (24u << 20) + (1u << 19));
    unsigned short* Qb  = (unsigned short*)(w + (25u << 20));
    unsigned short* Kb  = Qb + (8u << 20);          // +16 MiB (elements!)
    unsigned short* Vtb = Kb + (8u << 20);          // +16 MiB
    unsigned short* Ob  = xb;                       // reuse x's slot
    float* Opart = (float*)(w + (73u << 20));       // 64 MiB
    float* Lpart = (float*)(w + (137u << 20));      // 1 MiB

    prologue_kernel<<<dim3(6401), 256, 0, stream>>>(x, q_w, k_w, v_w, o_w,
                                                    xb, wq, wk, wv, wo,
                                                    cosT, sinT, mask, m64);

    gemm_qkvt<<<dim3(24, 64), 256, 0, stream>>>(xb, wq, wk, wv, q_b, k_b, v_b,
                                                Qb, Kb, Vtb, cosT, sinT);

    if (ws_size >= (138ull << 20)) {
        attn_part<<<dim3(2048), 256, 0, stream>>>(Qb, Kb, Vtb, m64, Opart, Lpart);
        attn_norm<<<dim3(1024), 256, 0, stream>>>(Opart, Lpart, Ob);
    } else {
        attn_kernel<<<dim3(1024), 256, 0, stream>>>(Qb, Kb, Vtb, m64, Ob);
    }

    gemm_bt<<<dim3(DIMN / 128, MROWS / 128), 256, 0, stream>>>(Ob, wo, o_b, out);
}